// Round 3
// baseline (1631.420 us; speedup 1.0000x reference)
//
#include <hip/hip_runtime.h>
#include <hip/hip_bf16.h>
#include <math.h>

#define B_ 8
#define W_ 1024
#define D_ 1024
#define R_ 64

typedef __hip_bfloat16 bf16;

__device__ __forceinline__ float tof(float x) { return x; }
__device__ __forceinline__ float tof(bf16 x) { return __bfloat162float(x); }

// ---------------------------------------------------------------------------
// RMSNorm: one block (256 threads) per row of D_=1024. fp32 in, bf16 out.
// ---------------------------------------------------------------------------
__global__ __launch_bounds__(256)
void rmsnorm_kernel(const float* __restrict__ src, const float* __restrict__ scale,
                    bf16* __restrict__ dst) {
    int row = blockIdx.x;
    const float* x = src + (size_t)row * D_;
    bf16* y = dst + (size_t)row * D_;
    float xv[4];
    float ss = 0.f;
#pragma unroll
    for (int it = 0; it < 4; ++it) {
        int d = threadIdx.x + it * 256;
        xv[it] = x[d];
        ss += xv[it] * xv[it];
    }
#pragma unroll
    for (int off = 32; off; off >>= 1) ss += __shfl_down(ss, off, 64);
    __shared__ float red[4];
    __shared__ float invs;
    int lane = threadIdx.x & 63, wid = threadIdx.x >> 6;
    if (lane == 0) red[wid] = ss;
    __syncthreads();
    if (threadIdx.x == 0) {
        float t = red[0] + red[1] + red[2] + red[3];
        invs = rsqrtf(t / (float)D_ + 1e-8f);
    }
    __syncthreads();
    float inv = invs;
#pragma unroll
    for (int it = 0; it < 4; ++it) {
        int d = threadIdx.x + it * 256;
        y[d] = __float2bfloat16(xv[it] * inv * scale[d]);
    }
}

// ---------------------------------------------------------------------------
// q/k projection + l2norm + per-rank gamma decay factorization.
// One block (128 threads = 2 waves) per (b,i) row. Wave 0 -> q, wave 1 -> k.
// qg[b,i,r] = l2norm(h_norm@u)[r] * gamma_r^i
// kg[b,i,r] = l2norm(h_norm@v)[r] * gamma_r^{-i}   (fp32: needs range+mantissa)
// ---------------------------------------------------------------------------
__global__ __launch_bounds__(128)
void qk_kernel(const bf16* __restrict__ hnorm,
               const float* __restrict__ u, const float* __restrict__ v,
               const float* __restrict__ decay_logit,
               float* __restrict__ qg, float* __restrict__ kg) {
    int row = blockIdx.x;          // b*W + i
    int i = row & (W_ - 1);
    __shared__ float hrow[D_];
    for (int d = threadIdx.x; d < D_; d += 128)
        hrow[d] = tof(hnorm[(size_t)row * D_ + d]);
    __syncthreads();

    int t = threadIdx.x;
    int r = t & 63;
    bool isK = t >= 64;
    const float* wmat = isK ? v : u;
    float acc = 0.f;
    for (int d = 0; d < D_; ++d)
        acc += hrow[d] * wmat[d * R_ + r];

    float sq = acc * acc;
#pragma unroll
    for (int off = 32; off; off >>= 1) sq += __shfl_xor(sq, off, 64);
    float val = acc / fmaxf(sqrtf(sq), 1e-8f);

    float dl = decay_logit[r];
    float gamma = 0.15f + 0.85f * (1.f / (1.f + expf(-dl)));
    float lg = logf(gamma);
    float e = isK ? expf(-(float)i * lg) : expf((float)i * lg);
    float o = val * e;
    if (isK) kg[(size_t)row * R_ + r] = o;
    else     qg[(size_t)row * R_ + r] = o;
}

// ---------------------------------------------------------------------------
// M[b,i,j] = (j<=i) ? gate*k_base[i,j] + alpha * dot(qg[b,i,:], kg[b,j,:]) : 0
// Block (16,16) computes a 32x32 tile (2x2 per thread). Output bf16.
// ---------------------------------------------------------------------------
__global__ __launch_bounds__(256)
void buildM_kernel(const float* __restrict__ qg, const float* __restrict__ kg,
                   const float* __restrict__ k_base,
                   const float* __restrict__ gate_logit,
                   const float* __restrict__ alpha_logit,
                   bf16* __restrict__ M) {
    int b = blockIdx.z;
    int ti = blockIdx.y, tj = blockIdx.x;
    int i0 = ti * 32, j0 = tj * 32;
    int tx = threadIdx.x, ty = threadIdx.y;
    bf16* Mb = M + (size_t)b * W_ * W_;
    const bf16 zero = __float2bfloat16(0.f);

    if (tj > ti) {  // fully above diagonal: zero
#pragma unroll
        for (int a = 0; a < 2; ++a)
#pragma unroll
            for (int c = 0; c < 2; ++c)
                Mb[(size_t)(i0 + ty * 2 + a) * W_ + (j0 + tx * 2 + c)] = zero;
        return;
    }

    __shared__ float Qs[32][65];
    __shared__ float Ks[32][65];
    int tid = ty * 16 + tx;
    for (int e = tid; e < 32 * 64; e += 256) {
        int rr = e & 63, row = e >> 6;
        Qs[row][rr] = qg[((size_t)b * W_ + i0 + row) * R_ + rr];
        Ks[row][rr] = kg[((size_t)b * W_ + j0 + row) * R_ + rr];
    }
    __syncthreads();

    float acc[2][2] = {{0.f, 0.f}, {0.f, 0.f}};
#pragma unroll 8
    for (int r = 0; r < 64; ++r) {
        float qa = Qs[ty * 2 + 0][r], qb = Qs[ty * 2 + 1][r];
        float ka = Ks[tx * 2 + 0][r], kb = Ks[tx * 2 + 1][r];
        acc[0][0] += qa * ka; acc[0][1] += qa * kb;
        acc[1][0] += qb * ka; acc[1][1] += qb * kb;
    }

    float gate  = 1.f / (1.f + expf(-(*gate_logit)));
    float alpha = 1.f / (1.f + expf(-(*alpha_logit)));  // ALPHA_CAP = 1
#pragma unroll
    for (int a = 0; a < 2; ++a) {
#pragma unroll
        for (int c = 0; c < 2; ++c) {
            int i = i0 + ty * 2 + a, j = j0 + tx * 2 + c;
            float vkb = k_base[(size_t)i * W_ + j];
            float out = (j <= i) ? (gate * vkb + alpha * acc[a][c]) : 0.f;
            Mb[(size_t)i * W_ + j] = __float2bfloat16(out);
        }
    }
}

// ---------------------------------------------------------------------------
// Tiled GEMM, fp32 accumulate: C[m,n] = sum_k A[m,k] * (BT ? B[n,k] : B[k,n])
// BM=BN=64, BK=16, block (16,16), 4x4 per thread.
// EPI 0: plain store (batched via sA/sB/sC)
// EPI 1: store acc + bias[n] + Res[idx]   (Res may alias Cout; same-index RMW)
// EPI 2: store gelu_exact(acc + bias[n])
// ---------------------------------------------------------------------------
template<typename TA, typename TB, typename TRES, typename TOUT, bool BT, int EPI>
__global__ __launch_bounds__(256)
void gemm_kernel(const TA* __restrict__ A, const TB* __restrict__ Bm,
                 const TRES* __restrict__ Res, const float* __restrict__ bias,
                 TOUT* __restrict__ Cout,
                 int M, int N, int K,
                 long sA, long sB, long sC,
                 int causal) {
    const TA* Ab = A + (size_t)blockIdx.z * sA;
    const TB* Bb = Bm + (size_t)blockIdx.z * sB;
    int m0 = blockIdx.y * 64, n0 = blockIdx.x * 64;
    int tx = threadIdx.x, ty = threadIdx.y;
    int tid = ty * 16 + tx;
    __shared__ __align__(16) float As[16][68];
    __shared__ __align__(16) float Bs[16][68];
    float acc[4][4] = {};
    int kmax = causal ? (m0 + 64 < K ? m0 + 64 : K) : K;

    for (int k0 = 0; k0 < kmax; k0 += 16) {
#pragma unroll
        for (int e = 0; e < 4; ++e) {
            int idx = tid + e * 256;
            int m = idx >> 4, kk = idx & 15;
            As[kk][m] = tof(Ab[(size_t)(m0 + m) * K + (k0 + kk)]);
        }
        if constexpr (BT) {
#pragma unroll
            for (int e = 0; e < 4; ++e) {
                int idx = tid + e * 256;
                int n = idx >> 4, kk = idx & 15;
                Bs[kk][n] = tof(Bb[(size_t)(n0 + n) * K + (k0 + kk)]);
            }
        } else {
#pragma unroll
            for (int e = 0; e < 4; ++e) {
                int idx = tid + e * 256;
                int kk = idx >> 6, n = idx & 63;
                Bs[kk][n] = tof(Bb[(size_t)(k0 + kk) * N + (n0 + n)]);
            }
        }
        __syncthreads();
#pragma unroll
        for (int kk = 0; kk < 16; ++kk) {
            float4 av = *reinterpret_cast<const float4*>(&As[kk][ty * 4]);
            float4 bv = *reinterpret_cast<const float4*>(&Bs[kk][tx * 4]);
            float a_[4] = {av.x, av.y, av.z, av.w};
            float b_[4] = {bv.x, bv.y, bv.z, bv.w};
#pragma unroll
            for (int i = 0; i < 4; ++i)
#pragma unroll
                for (int j = 0; j < 4; ++j)
                    acc[i][j] += a_[i] * b_[j];
        }
        __syncthreads();
    }

#pragma unroll
    for (int i = 0; i < 4; ++i) {
        int m = m0 + ty * 4 + i;
#pragma unroll
        for (int j = 0; j < 4; ++j) {
            int n = n0 + tx * 4 + j;
            size_t idx = (size_t)m * N + n;
            float val = acc[i][j];
            if constexpr (EPI == 0) {
                Cout[(size_t)blockIdx.z * sC + idx] = (TOUT)__float2bfloat16(val);
            } else if constexpr (EPI == 1) {
                val += bias[n] + tof(Res[idx]);
                Cout[idx] = val;
            } else {
                val += bias[n];
                val = 0.5f * val * (1.f + erff(val * 0.70710678118654752f));
                Cout[idx] = (TOUT)__float2bfloat16(val);
            }
        }
    }
}

// ---------------------------------------------------------------------------
// Inputs/output are fp32 (per the reference's dtypes — round 0/1 NaNs were
// caused by reinterpreting fp32 inputs as bf16). Intermediates bf16 in ws.
// Workspace (peak 52 MB):
//   [0,16)  MB : hnorm bf16 (B*W*D), reused for mnorm after step 5
//   [16,18) MB : qg fp32 (B*W*R)
//   [18,20) MB : kg fp32
//   [20,36) MB : M bf16 (B*W*W)    -+ reused as tbuf bf16 (B*W*2D, 32 MB)
//   [36,52) MB : attn bf16 (B*W*D) -+
//   h1 lives in d_out (fp32, 32 MB); final epilogue same-index RMW (safe).
// ---------------------------------------------------------------------------
extern "C" void kernel_launch(void* const* d_in, const int* in_sizes, int n_in,
                              void* d_out, int out_size, void* d_ws, size_t ws_size,
                              hipStream_t stream) {
    const float* h           = (const float*)d_in[0];
    const float* k_base      = (const float*)d_in[1];
    const float* decay_logit = (const float*)d_in[2];
    const float* gate_logit  = (const float*)d_in[3];
    const float* alpha_logit = (const float*)d_in[4];
    const float* u           = (const float*)d_in[5];
    const float* v           = (const float*)d_in[6];
    const float* proj_w      = (const float*)d_in[7];
    const float* proj_b      = (const float*)d_in[8];
    const float* norm1_scale = (const float*)d_in[9];
    const float* norm2_scale = (const float*)d_in[10];
    const float* up_w        = (const float*)d_in[11];
    const float* up_b        = (const float*)d_in[12];
    const float* down_w      = (const float*)d_in[13];
    const float* down_b      = (const float*)d_in[14];

    char* ws = (char*)d_ws;
    bf16*  hnorm = (bf16*)(ws);                          // 16 MB
    float* qg    = (float*)(ws + (size_t)16 * 1048576);  //  2 MB
    float* kg    = (float*)(ws + (size_t)18 * 1048576);  //  2 MB
    bf16*  Mbuf  = (bf16*)(ws + (size_t)20 * 1048576);   // 16 MB
    bf16*  attn  = (bf16*)(ws + (size_t)36 * 1048576);   // 16 MB
    bf16*  tbuf  = Mbuf;                                 // 32 MB (M+attn region)
    float* h1    = (float*)d_out;                        // lives in d_out

    // 1. h_norm = rmsnorm(h, norm1_scale)
    rmsnorm_kernel<<<B_ * W_, 256, 0, stream>>>(h, norm1_scale, hnorm);

    // 2. q/k with decay factorization
    qk_kernel<<<B_ * W_, 128, 0, stream>>>(hnorm, u, v, decay_logit, qg, kg);

    // 3. M = causal * (gate*k_base + alpha*scores)
    buildM_kernel<<<dim3(W_ / 32, W_ / 32, B_), dim3(16, 16), 0, stream>>>(
        qg, kg, k_base, gate_logit, alpha_logit, Mbuf);

    // 4. attn = M @ h_norm   (batched, causal k-truncation)
    gemm_kernel<bf16, bf16, float, bf16, false, 0>
        <<<dim3(16, 16, B_), dim3(16, 16), 0, stream>>>(
        Mbuf, hnorm, nullptr, nullptr, attn, W_, D_, W_,
        (long)W_ * W_, (long)W_ * D_, (long)W_ * D_, 1);

    // 5. h1 = h + attn @ proj_w^T + proj_b   -> d_out (fp32)
    gemm_kernel<bf16, float, float, float, true, 1>
        <<<dim3(16, 128, 1), dim3(16, 16), 0, stream>>>(
        attn, proj_w, h, proj_b, h1, B_ * W_, D_, D_, 0, 0, 0, 0);

    // 6. mnorm = rmsnorm(h1, norm2_scale)  (reuses hnorm buffer)
    rmsnorm_kernel<<<B_ * W_, 256, 0, stream>>>(h1, norm2_scale, hnorm);

    // 7. t = gelu(mnorm @ up_w^T + up_b)    -> tbuf (bf16)
    gemm_kernel<bf16, float, float, bf16, true, 2>
        <<<dim3(32, 128, 1), dim3(16, 16), 0, stream>>>(
        hnorm, up_w, nullptr, up_b, tbuf, B_ * W_, 2 * D_, D_, 0, 0, 0, 0);

    // 8. out = h1 + t @ down_w^T + down_b   (h1 aliases d_out: same-idx RMW)
    gemm_kernel<bf16, float, float, float, true, 1>
        <<<dim3(16, 128, 1), dim3(16, 16), 0, stream>>>(
        tbuf, down_w, h1, down_b, (float*)d_out, B_ * W_, D_, 2 * D_, 0, 0, 0, 0);
}

// Round 4
// 579.831 us; speedup vs baseline: 2.8136x; 2.8136x over previous
//
#include <hip/hip_runtime.h>
#include <hip/hip_bf16.h>
#include <math.h>

#define B_ 8
#define W_ 1024
#define D_ 1024
#define R_ 64

typedef __hip_bfloat16 bf16;
typedef __attribute__((ext_vector_type(8))) short bf16x8;   // MFMA A/B frag (4 VGPRs)
typedef __attribute__((ext_vector_type(4))) float f32x4;    // MFMA C/D frag

__device__ __forceinline__ float tof(bf16 x) { return __bfloat162float(x); }
__device__ __forceinline__ short f2bs(float f) {
    bf16 b = __float2bfloat16(f);
    return *(short*)&b;
}

// async global->LDS, 16 bytes/lane; LDS dest = wave-uniform base + lane*16
__device__ __forceinline__ void async16(const void* g, void* l) {
    __builtin_amdgcn_global_load_lds(
        (const __attribute__((address_space(1))) unsigned int*)g,
        (__attribute__((address_space(3))) unsigned int*)l,
        16, 0, 0);
}

// ---------------------------------------------------------------------------
// RMSNorm: one block (256 threads) per row of D_=1024. fp32 in, bf16 out.
// ---------------------------------------------------------------------------
__global__ __launch_bounds__(256)
void rmsnorm_kernel(const float* __restrict__ src, const float* __restrict__ scale,
                    bf16* __restrict__ dst) {
    int row = blockIdx.x;
    const float* x = src + (size_t)row * D_;
    bf16* y = dst + (size_t)row * D_;
    float xv[4];
    float ss = 0.f;
#pragma unroll
    for (int it = 0; it < 4; ++it) {
        int d = threadIdx.x + it * 256;
        xv[it] = x[d];
        ss += xv[it] * xv[it];
    }
#pragma unroll
    for (int off = 32; off; off >>= 1) ss += __shfl_down(ss, off, 64);
    __shared__ float red[4];
    __shared__ float invs;
    int lane = threadIdx.x & 63, wid = threadIdx.x >> 6;
    if (lane == 0) red[wid] = ss;
    __syncthreads();
    if (threadIdx.x == 0) {
        float t = red[0] + red[1] + red[2] + red[3];
        invs = rsqrtf(t / (float)D_ + 1e-8f);
    }
    __syncthreads();
    float inv = invs;
#pragma unroll
    for (int it = 0; it < 4; ++it) {
        int d = threadIdx.x + it * 256;
        y[d] = __float2bfloat16(xv[it] * inv * scale[d]);
    }
}

// ---------------------------------------------------------------------------
// 64x64 LDS-tiled transpose: src[b][j][d] -> dst[b][d][j]  (bf16)
// ---------------------------------------------------------------------------
__global__ __launch_bounds__(256)
void transpose_kernel(const bf16* __restrict__ src, bf16* __restrict__ dst) {
    int b = blockIdx.z;
    int j0 = blockIdx.x * 64, d0 = blockIdx.y * 64;
    __shared__ short Ts[64][72];
    const bf16* S = src + (size_t)b * W_ * D_;
    bf16* Dd = dst + (size_t)b * W_ * D_;
    int tid = threadIdx.x;
    int r = tid >> 3, c = (tid & 7) * 8;
#pragma unroll
    for (int p = 0; p < 2; ++p) {
        int j = r + p * 32;
        bf16x8 vv = *(const bf16x8*)&S[(size_t)(j0 + j) * D_ + d0 + c];
#pragma unroll
        for (int e = 0; e < 8; ++e) Ts[j][c + e] = vv[e];
    }
    __syncthreads();
#pragma unroll
    for (int p = 0; p < 2; ++p) {
        int d = r + p * 32;
        bf16x8 vv;
#pragma unroll
        for (int e = 0; e < 8; ++e) vv[e] = Ts[c + e][d];
        *(bf16x8*)&Dd[(size_t)(d0 + d) * W_ + j0 + c] = vv;
    }
}

// ---------------------------------------------------------------------------
// q/k projection + l2norm + per-rank gamma decay factorization.
// ---------------------------------------------------------------------------
__global__ __launch_bounds__(128)
void qk_kernel(const bf16* __restrict__ hnorm,
               const float* __restrict__ u, const float* __restrict__ v,
               const float* __restrict__ decay_logit,
               float* __restrict__ qg, float* __restrict__ kg) {
    int row = blockIdx.x;          // b*W + i
    int i = row & (W_ - 1);
    __shared__ float hrow[D_];
    for (int d = threadIdx.x; d < D_; d += 128)
        hrow[d] = tof(hnorm[(size_t)row * D_ + d]);
    __syncthreads();

    int t = threadIdx.x;
    int r = t & 63;
    bool isK = t >= 64;
    const float* wmat = isK ? v : u;
    float acc = 0.f;
    for (int d = 0; d < D_; ++d)
        acc += hrow[d] * wmat[d * R_ + r];

    float sq = acc * acc;
#pragma unroll
    for (int off = 32; off; off >>= 1) sq += __shfl_xor(sq, off, 64);
    float val = acc / fmaxf(sqrtf(sq), 1e-8f);

    float dl = decay_logit[r];
    float gamma = 0.15f + 0.85f * (1.f / (1.f + expf(-dl)));
    float lg = logf(gamma);
    float e = isK ? expf(-(float)i * lg) : expf((float)i * lg);
    float o = val * e;
    if (isK) kg[(size_t)row * R_ + r] = o;
    else     qg[(size_t)row * R_ + r] = o;
}

// ---------------------------------------------------------------------------
// M[b,i,j] = (j<=i) ? gate*k_base[i,j] + alpha * dot(qg[b,i,:], kg[b,j,:]) : 0
// ---------------------------------------------------------------------------
__global__ __launch_bounds__(256)
void buildM_kernel(const float* __restrict__ qg, const float* __restrict__ kg,
                   const float* __restrict__ k_base,
                   const float* __restrict__ gate_logit,
                   const float* __restrict__ alpha_logit,
                   bf16* __restrict__ M) {
    int b = blockIdx.z;
    int ti = blockIdx.y, tj = blockIdx.x;
    int i0 = ti * 32, j0 = tj * 32;
    int tx = threadIdx.x, ty = threadIdx.y;
    bf16* Mb = M + (size_t)b * W_ * W_;
    const bf16 zero = __float2bfloat16(0.f);

    if (tj > ti) {
#pragma unroll
        for (int a = 0; a < 2; ++a)
#pragma unroll
            for (int c = 0; c < 2; ++c)
                Mb[(size_t)(i0 + ty * 2 + a) * W_ + (j0 + tx * 2 + c)] = zero;
        return;
    }

    __shared__ float Qs[32][65];
    __shared__ float Ks[32][65];
    int tid = ty * 16 + tx;
    for (int e = tid; e < 32 * 64; e += 256) {
        int rr = e & 63, row = e >> 6;
        Qs[row][rr] = qg[((size_t)b * W_ + i0 + row) * R_ + rr];
        Ks[row][rr] = kg[((size_t)b * W_ + j0 + row) * R_ + rr];
    }
    __syncthreads();

    float acc[2][2] = {{0.f, 0.f}, {0.f, 0.f}};
#pragma unroll 8
    for (int r = 0; r < 64; ++r) {
        float qa = Qs[ty * 2 + 0][r], qb = Qs[ty * 2 + 1][r];
        float ka = Ks[tx * 2 + 0][r], kb = Ks[tx * 2 + 1][r];
        acc[0][0] += qa * ka; acc[0][1] += qa * kb;
        acc[1][0] += qb * ka; acc[1][1] += qb * kb;
    }

    float gate  = 1.f / (1.f + expf(-(*gate_logit)));
    float alpha = 1.f / (1.f + expf(-(*alpha_logit)));  // ALPHA_CAP = 1
#pragma unroll
    for (int a = 0; a < 2; ++a) {
#pragma unroll
        for (int c = 0; c < 2; ++c) {
            int i = i0 + ty * 2 + a, j = j0 + tx * 2 + c;
            float vkb = k_base[(size_t)i * W_ + j];
            float out = (j <= i) ? (gate * vkb + alpha * acc[a][c]) : 0.f;
            Mb[(size_t)i * W_ + j] = __float2bfloat16(out);
        }
    }
}

// ---------------------------------------------------------------------------
// MFMA GEMM: C[m,n] = sum_k A[m,k]*B[n,k]  (both operands B^T/row-major-in-k)
// BM=BN=128, BK=32; 256 threads = 4 waves in 2x2; each wave 4x4 MFMA tiles
// of 16x16x32 bf16. A: bf16, staged via global_load_lds (16B/lane).
// B: TB=bf16 -> async staging; TB=float -> VGPR load + cvt + ds_write.
// Fragment layouts (HW-verified, learn_hip m89/m92/m120):
//   A/B frag: row = lane&15 (within tile), k = (lane>>4)*8 + j  -> ds_read_b128
//   C/D:      col = lane&15, row = (lane>>4)*4 + reg
// EPI 0: Cout bf16 = acc                       (batched via sC)
// EPI 1: Cout fp32 = acc + bias[n] + Res[idx]  (Res may alias Cout, same-idx)
// EPI 2: Cout bf16 = gelu_exact(acc + bias[n])
// ---------------------------------------------------------------------------
template<typename TB, int EPI>
__global__ __launch_bounds__(256)
void mgemm_kernel(const bf16* __restrict__ A, const TB* __restrict__ Bm,
                  const float* __restrict__ Res, const float* __restrict__ bias,
                  void* __restrict__ Cout,
                  int M, int N, int K,
                  long sA, long sB, long sC, int causal) {
    __shared__ __align__(16) short At[128 * 32];
    __shared__ __align__(16) short Bt[128 * 32];
    const bf16* Ab = A + (size_t)blockIdx.z * sA;
    const TB* Bb = Bm + (size_t)blockIdx.z * sB;
    int m0 = blockIdx.y * 128, n0 = blockIdx.x * 128;
    int tid = threadIdx.x;
    int lane = tid & 63, wave = tid >> 6;
    int wy = wave >> 1, wx = wave & 1;
    int quad = lane >> 4, l15 = lane & 15;

    f32x4 acc[4][4];
#pragma unroll
    for (int i = 0; i < 4; ++i)
#pragma unroll
        for (int j = 0; j < 4; ++j)
            acc[i][j] = (f32x4){0.f, 0.f, 0.f, 0.f};

    int kmax = causal ? (m0 + 128 < K ? m0 + 128 : K) : K;

    // async-staging geometry: issue i covers tile rows [i*64+wave*16, +16)
    int srow = wave * 16 + (lane >> 2);      // + 64*i
    int scol = (lane & 3) * 8;               // k-elems within row
    // fp32-B staging geometry: thread covers Bt row tid/2, k-elems (tid&1)*16..+16
    int brow = tid >> 1;
    int bk = (tid & 1) * 16;

    for (int k0 = 0; k0 < kmax; k0 += 32) {
        // ---- stage A (async, 2 issues x 16B/lane) ----
        async16(Ab + (size_t)(m0 + srow) * K + k0 + scol,
                (short*)At + wave * 512);
        async16(Ab + (size_t)(m0 + 64 + srow) * K + k0 + scol,
                (short*)At + 2048 + wave * 512);
        // ---- stage B ----
        if constexpr (sizeof(TB) == 2) {
            async16((const bf16*)Bb + (size_t)(n0 + srow) * K + k0 + scol,
                    (short*)Bt + wave * 512);
            async16((const bf16*)Bb + (size_t)(n0 + 64 + srow) * K + k0 + scol,
                    (short*)Bt + 2048 + wave * 512);
        } else {
            const float* bg = (const float*)Bb + (size_t)(n0 + brow) * K + k0 + bk;
            float4 f0 = *(const float4*)(bg + 0);
            float4 f1 = *(const float4*)(bg + 4);
            float4 f2 = *(const float4*)(bg + 8);
            float4 f3 = *(const float4*)(bg + 12);
            bf16x8 p0, p1;
            p0[0] = f2bs(f0.x); p0[1] = f2bs(f0.y); p0[2] = f2bs(f0.z); p0[3] = f2bs(f0.w);
            p0[4] = f2bs(f1.x); p0[5] = f2bs(f1.y); p0[6] = f2bs(f1.z); p0[7] = f2bs(f1.w);
            p1[0] = f2bs(f2.x); p1[1] = f2bs(f2.y); p1[2] = f2bs(f2.z); p1[3] = f2bs(f2.w);
            p1[4] = f2bs(f3.x); p1[5] = f2bs(f3.y); p1[6] = f2bs(f3.z); p1[7] = f2bs(f3.w);
            *(bf16x8*)&Bt[brow * 32 + bk] = p0;
            *(bf16x8*)&Bt[brow * 32 + bk + 8] = p1;
        }
        __syncthreads();   // drains vmcnt (async) + lgkmcnt before reads

        bf16x8 af[4], bfr[4];
#pragma unroll
        for (int mi = 0; mi < 4; ++mi)
            af[mi] = *(const bf16x8*)&At[(wy * 64 + mi * 16 + l15) * 32 + quad * 8];
#pragma unroll
        for (int ni = 0; ni < 4; ++ni)
            bfr[ni] = *(const bf16x8*)&Bt[(wx * 64 + ni * 16 + l15) * 32 + quad * 8];
#pragma unroll
        for (int mi = 0; mi < 4; ++mi)
#pragma unroll
            for (int ni = 0; ni < 4; ++ni)
                acc[mi][ni] = __builtin_amdgcn_mfma_f32_16x16x32_bf16(
                    af[mi], bfr[ni], acc[mi][ni], 0, 0, 0);
        __syncthreads();   // protect tiles before next stage
    }

    // ---- epilogue ----
#pragma unroll
    for (int ni = 0; ni < 4; ++ni) {
        int col = n0 + wx * 64 + ni * 16 + l15;
        float bv = (EPI != 0) ? bias[col] : 0.f;
#pragma unroll
        for (int mi = 0; mi < 4; ++mi) {
            int row0 = m0 + wy * 64 + mi * 16 + quad * 4;
#pragma unroll
            for (int r = 0; r < 4; ++r) {
                size_t idx = (size_t)(row0 + r) * N + col;
                float val = acc[mi][ni][r];
                if constexpr (EPI == 0) {
                    ((bf16*)Cout)[(size_t)blockIdx.z * sC + idx] = __float2bfloat16(val);
                } else if constexpr (EPI == 1) {
                    ((float*)Cout)[idx] = val + bv + Res[idx];
                } else {
                    val += bv;
                    val = 0.5f * val * (1.f + erff(val * 0.70710678118654752f));
                    ((bf16*)Cout)[idx] = __float2bfloat16(val);
                }
            }
        }
    }
}

// ---------------------------------------------------------------------------
// Workspace (peak 52 MB — identical footprint to the passing round-3 layout):
//   [0,16)  MB : hnorm bf16 (steps 1-3) -> attn bf16 (4->5) -> mnorm bf16 (6->7)
//   [16,20) MB : qg/kg fp32 (2->4)
//   [20,36) MB : hnormT bf16 [b][d][j] (2->5)  -+ tbuf bf16 (7->8) reuses [20,52)
//   [36,52) MB : M bf16 (4->5)                 -+
//   h1 lives in d_out (fp32); final GEMM does same-index RMW (alias-safe).
// ---------------------------------------------------------------------------
extern "C" void kernel_launch(void* const* d_in, const int* in_sizes, int n_in,
                              void* d_out, int out_size, void* d_ws, size_t ws_size,
                              hipStream_t stream) {
    const float* h           = (const float*)d_in[0];
    const float* k_base      = (const float*)d_in[1];
    const float* decay_logit = (const float*)d_in[2];
    const float* gate_logit  = (const float*)d_in[3];
    const float* alpha_logit = (const float*)d_in[4];
    const float* u           = (const float*)d_in[5];
    const float* v           = (const float*)d_in[6];
    const float* proj_w      = (const float*)d_in[7];
    const float* proj_b      = (const float*)d_in[8];
    const float* norm1_scale = (const float*)d_in[9];
    const float* norm2_scale = (const float*)d_in[10];
    const float* up_w        = (const float*)d_in[11];
    const float* up_b        = (const float*)d_in[12];
    const float* down_w      = (const float*)d_in[13];
    const float* down_b      = (const float*)d_in[14];

    char* ws = (char*)d_ws;
    bf16*  hnorm  = (bf16*)(ws);                          // 16 MB
    float* qg     = (float*)(ws + (size_t)16 * 1048576);  //  2 MB
    float* kg     = (float*)(ws + (size_t)18 * 1048576);  //  2 MB
    bf16*  hnormT = (bf16*)(ws + (size_t)20 * 1048576);   // 16 MB
    bf16*  Mbuf   = (bf16*)(ws + (size_t)36 * 1048576);   // 16 MB
    bf16*  attn   = hnorm;                                // [0,16) after qk
    bf16*  mnorm  = hnorm;                                // [0,16) after step 5
    bf16*  tbuf   = hnormT;                               // [20,52) after step 4
    float* h1     = (float*)d_out;

    // 1. h_norm = rmsnorm(h, norm1_scale)
    rmsnorm_kernel<<<B_ * W_, 256, 0, stream>>>(h, norm1_scale, hnorm);

    // 1b. hnormT[b][d][j] = hnorm[b][j][d]
    transpose_kernel<<<dim3(W_ / 64, D_ / 64, B_), 256, 0, stream>>>(hnorm, hnormT);

    // 2. q/k with decay factorization
    qk_kernel<<<B_ * W_, 128, 0, stream>>>(hnorm, u, v, decay_logit, qg, kg);

    // 3. M = causal * (gate*k_base + alpha*scores)
    buildM_kernel<<<dim3(W_ / 32, W_ / 32, B_), dim3(16, 16), 0, stream>>>(
        qg, kg, k_base, gate_logit, alpha_logit, Mbuf);

    // 4. attn = M @ hnorm  (B-operand = hnormT, batched, causal k-truncation)
    mgemm_kernel<bf16, 0><<<dim3(D_ / 128, W_ / 128, B_), 256, 0, stream>>>(
        Mbuf, hnormT, nullptr, nullptr, attn, W_, D_, W_,
        (long)W_ * W_, (long)W_ * D_, (long)W_ * D_, 1);

    // 5. h1 = h + attn @ proj_w^T + proj_b   -> d_out (fp32)
    mgemm_kernel<float, 1><<<dim3(D_ / 128, B_ * W_ / 128, 1), 256, 0, stream>>>(
        attn, proj_w, h, proj_b, h1, B_ * W_, D_, D_, 0, 0, 0, 0);

    // 6. mnorm = rmsnorm(h1, norm2_scale)
    rmsnorm_kernel<<<B_ * W_, 256, 0, stream>>>(h1, norm2_scale, mnorm);

    // 7. t = gelu(mnorm @ up_w^T + up_b)     -> tbuf (bf16)
    mgemm_kernel<float, 2><<<dim3(2 * D_ / 128, B_ * W_ / 128, 1), 256, 0, stream>>>(
        mnorm, up_w, nullptr, up_b, tbuf, B_ * W_, 2 * D_, D_, 0, 0, 0, 0);

    // 8. out = h1 + t @ down_w^T + down_b    (h1 aliases d_out: same-idx RMW)
    mgemm_kernel<float, 1><<<dim3(D_ / 128, B_ * W_ / 128, 1), 256, 0, stream>>>(
        tbuf, down_w, h1, down_b, (float*)d_out, B_ * W_, D_, 2 * D_, 0, 0, 0, 0);
}

// Round 5
// 412.198 us; speedup vs baseline: 3.9579x; 1.4067x over previous
//
#include <hip/hip_runtime.h>
#include <hip/hip_bf16.h>
#include <math.h>

#define B_ 8
#define W_ 1024
#define D_ 1024
#define R_ 64

typedef __hip_bfloat16 bf16;
typedef __attribute__((ext_vector_type(8))) short bf16x8;   // MFMA A/B frag (4 VGPRs)
typedef __attribute__((ext_vector_type(4))) float f32x4;    // MFMA C/D frag

__device__ __forceinline__ float tof(bf16 x) { return __bfloat162float(x); }
__device__ __forceinline__ short f2bs(float f) {
    bf16 b = __float2bfloat16(f);
    return *(short*)&b;
}

// async global->LDS, 16 bytes/lane; LDS dest = wave-uniform base + lane*16
__device__ __forceinline__ void async16(const void* g, void* l) {
    __builtin_amdgcn_global_load_lds(
        (const __attribute__((address_space(1))) unsigned int*)g,
        (__attribute__((address_space(3))) unsigned int*)l,
        16, 0, 0);
}

// ---------------------------------------------------------------------------
// RMSNorm: one block (256 threads) per row of D_=1024. fp32 in, bf16 out.
// ---------------------------------------------------------------------------
__global__ __launch_bounds__(256)
void rmsnorm_kernel(const float* __restrict__ src, const float* __restrict__ scale,
                    bf16* __restrict__ dst) {
    int row = blockIdx.x;
    const float* x = src + (size_t)row * D_;
    bf16* y = dst + (size_t)row * D_;
    float xv[4];
    float ss = 0.f;
#pragma unroll
    for (int it = 0; it < 4; ++it) {
        int d = threadIdx.x + it * 256;
        xv[it] = x[d];
        ss += xv[it] * xv[it];
    }
#pragma unroll
    for (int off = 32; off; off >>= 1) ss += __shfl_down(ss, off, 64);
    __shared__ float red[4];
    __shared__ float invs;
    int lane = threadIdx.x & 63, wid = threadIdx.x >> 6;
    if (lane == 0) red[wid] = ss;
    __syncthreads();
    if (threadIdx.x == 0) {
        float t = red[0] + red[1] + red[2] + red[3];
        invs = rsqrtf(t / (float)D_ + 1e-8f);
    }
    __syncthreads();
    float inv = invs;
#pragma unroll
    for (int it = 0; it < 4; ++it) {
        int d = threadIdx.x + it * 256;
        y[d] = __float2bfloat16(xv[it] * inv * scale[d]);
    }
}

// ---------------------------------------------------------------------------
// 64x64 LDS-tiled transpose: src[b][j][d] -> dst[b][d][j]  (bf16)
// ---------------------------------------------------------------------------
__global__ __launch_bounds__(256)
void transpose_kernel(const bf16* __restrict__ src, bf16* __restrict__ dst) {
    int b = blockIdx.z;
    int j0 = blockIdx.x * 64, d0 = blockIdx.y * 64;
    __shared__ short Ts[64][72];
    const bf16* S = src + (size_t)b * W_ * D_;
    bf16* Dd = dst + (size_t)b * W_ * D_;
    int tid = threadIdx.x;
    int r = tid >> 3, c = (tid & 7) * 8;
#pragma unroll
    for (int p = 0; p < 2; ++p) {
        int j = r + p * 32;
        bf16x8 vv = *(const bf16x8*)&S[(size_t)(j0 + j) * D_ + d0 + c];
#pragma unroll
        for (int e = 0; e < 8; ++e) Ts[j][c + e] = vv[e];
    }
    __syncthreads();
#pragma unroll
    for (int p = 0; p < 2; ++p) {
        int d = r + p * 32;
        bf16x8 vv;
#pragma unroll
        for (int e = 0; e < 8; ++e) vv[e] = Ts[c + e][d];
        *(bf16x8*)&Dd[(size_t)(d0 + d) * W_ + j0 + c] = vv;
    }
}

// ---------------------------------------------------------------------------
// uvT[r][d] (bf16, [128][1024]) from u[d][64] (z=0) and v[d][64] (z=1).
// 64x64 LDS tile per block; grid (D/64, 1, 2).
// ---------------------------------------------------------------------------
__global__ __launch_bounds__(256)
void uvT_kernel(const float* __restrict__ u, const float* __restrict__ v,
                bf16* __restrict__ uvT) {
    int g = blockIdx.z;
    int d0 = blockIdx.x * 64;
    const float* src = g ? v : u;
    __shared__ float Ts[64][65];
    int tid = threadIdx.x;
#pragma unroll
    for (int e = 0; e < 16; ++e) {
        int idx = tid + e * 256;
        int drow = idx >> 6, rcol = idx & 63;
        Ts[drow][rcol] = src[(size_t)(d0 + drow) * 64 + rcol];
    }
    __syncthreads();
#pragma unroll
    for (int e = 0; e < 16; ++e) {
        int idx = tid + e * 256;
        int orow = idx >> 6, ocol = idx & 63;   // orow = r, ocol = d offset
        uvT[(size_t)(g * 64 + orow) * D_ + d0 + ocol] = __float2bfloat16(Ts[ocol][orow]);
    }
}

// ---------------------------------------------------------------------------
// fp32 -> bf16 elementwise convert (n multiple of 2048).
// ---------------------------------------------------------------------------
__global__ __launch_bounds__(256)
void convert_kernel(const float* __restrict__ src, bf16* __restrict__ dst, int n) {
    int idx = (blockIdx.x * 256 + threadIdx.x) * 8;
    if (idx >= n) return;
    float4 f0 = *(const float4*)(src + idx);
    float4 f1 = *(const float4*)(src + idx + 4);
    bf16x8 p;
    p[0] = f2bs(f0.x); p[1] = f2bs(f0.y); p[2] = f2bs(f0.z); p[3] = f2bs(f0.w);
    p[4] = f2bs(f1.x); p[5] = f2bs(f1.y); p[6] = f2bs(f1.z); p[7] = f2bs(f1.w);
    *(bf16x8*)(dst + idx) = p;
}

// ---------------------------------------------------------------------------
// qk epilogue: per (b,i) row of qkraw [8192][128] bf16:
//   wave 0 (r=0..63):  q = l2norm(row[0:64]);   qg = q * gamma_r^i
//   wave 1 (r=64..127):k = l2norm(row[64:128]); kg = k * gamma_r^{-i}
// ---------------------------------------------------------------------------
__global__ __launch_bounds__(128)
void qk_epilogue_kernel(const bf16* __restrict__ qkraw,
                        const float* __restrict__ decay_logit,
                        float* __restrict__ qg, float* __restrict__ kg) {
    int row = blockIdx.x;          // b*W + i
    int i = row & (W_ - 1);
    int t = threadIdx.x;
    int r = t & 63;
    bool isK = t >= 64;
    float val = tof(qkraw[(size_t)row * 128 + t]);
    float sq = val * val;
#pragma unroll
    for (int off = 32; off; off >>= 1) sq += __shfl_xor(sq, off, 64);
    val = val / fmaxf(sqrtf(sq), 1e-8f);

    float dl = decay_logit[r];
    float gamma = 0.15f + 0.85f * (1.f / (1.f + expf(-dl)));
    float lg = logf(gamma);
    float e = isK ? expf(-(float)i * lg) : expf((float)i * lg);
    float o = val * e;
    if (isK) kg[(size_t)row * R_ + r] = o;
    else     qg[(size_t)row * R_ + r] = o;
}

// ---------------------------------------------------------------------------
// M[b,i,j] = (j<=i) ? gate*k_base[i,j] + alpha * dot(qg[b,i,:], kg[b,j,:]) : 0
// ---------------------------------------------------------------------------
__global__ __launch_bounds__(256)
void buildM_kernel(const float* __restrict__ qg, const float* __restrict__ kg,
                   const float* __restrict__ k_base,
                   const float* __restrict__ gate_logit,
                   const float* __restrict__ alpha_logit,
                   bf16* __restrict__ M) {
    int b = blockIdx.z;
    int ti = blockIdx.y, tj = blockIdx.x;
    int i0 = ti * 32, j0 = tj * 32;
    int tx = threadIdx.x, ty = threadIdx.y;
    bf16* Mb = M + (size_t)b * W_ * W_;
    const bf16 zero = __float2bfloat16(0.f);

    if (tj > ti) {
#pragma unroll
        for (int a = 0; a < 2; ++a)
#pragma unroll
            for (int c = 0; c < 2; ++c)
                Mb[(size_t)(i0 + ty * 2 + a) * W_ + (j0 + tx * 2 + c)] = zero;
        return;
    }

    __shared__ float Qs[32][65];
    __shared__ float Ks[32][65];
    int tid = ty * 16 + tx;
    for (int e = tid; e < 32 * 64; e += 256) {
        int rr = e & 63, row = e >> 6;
        Qs[row][rr] = qg[((size_t)b * W_ + i0 + row) * R_ + rr];
        Ks[row][rr] = kg[((size_t)b * W_ + j0 + row) * R_ + rr];
    }
    __syncthreads();

    float acc[2][2] = {{0.f, 0.f}, {0.f, 0.f}};
#pragma unroll 8
    for (int r = 0; r < 64; ++r) {
        float qa = Qs[ty * 2 + 0][r], qb = Qs[ty * 2 + 1][r];
        float ka = Ks[tx * 2 + 0][r], kb = Ks[tx * 2 + 1][r];
        acc[0][0] += qa * ka; acc[0][1] += qa * kb;
        acc[1][0] += qb * ka; acc[1][1] += qb * kb;
    }

    float gate  = 1.f / (1.f + expf(-(*gate_logit)));
    float alpha = 1.f / (1.f + expf(-(*alpha_logit)));  // ALPHA_CAP = 1
#pragma unroll
    for (int a = 0; a < 2; ++a) {
#pragma unroll
        for (int c = 0; c < 2; ++c) {
            int i = i0 + ty * 2 + a, j = j0 + tx * 2 + c;
            float vkb = k_base[(size_t)i * W_ + j];
            float out = (j <= i) ? (gate * vkb + alpha * acc[a][c]) : 0.f;
            Mb[(size_t)i * W_ + j] = __float2bfloat16(out);
        }
    }
}

// ---------------------------------------------------------------------------
// MFMA GEMM: C[m,n] = sum_k A[m,k]*B[n,k]  (A, B both bf16, k-major)
// BM=BN=128, BK=32; 256 threads = 4 waves (2x2); wave does 4x4 of 16x16x32.
// All staging via global_load_lds 16B/lane.
// EPI 0: Cout bf16 = acc                       (batched via sC)
// EPI 1: Cout fp32 = acc + bias[n] + Res[idx]  (Res may alias Cout, same-idx)
// EPI 2: Cout bf16 = gelu_exact(acc + bias[n])
// ---------------------------------------------------------------------------
template<int EPI>
__global__ __launch_bounds__(256)
void mgemm_kernel(const bf16* __restrict__ A, const bf16* __restrict__ Bm,
                  const float* __restrict__ Res, const float* __restrict__ bias,
                  void* __restrict__ Cout,
                  int M, int N, int K,
                  long sA, long sB, long sC, int causal) {
    __shared__ __align__(16) short At[128 * 32];
    __shared__ __align__(16) short Bt[128 * 32];
    const bf16* Ab = A + (size_t)blockIdx.z * sA;
    const bf16* Bb = Bm + (size_t)blockIdx.z * sB;
    int m0 = blockIdx.y * 128, n0 = blockIdx.x * 128;
    int tid = threadIdx.x;
    int lane = tid & 63, wave = tid >> 6;
    int wy = wave >> 1, wx = wave & 1;
    int quad = lane >> 4, l15 = lane & 15;

    f32x4 acc[4][4];
#pragma unroll
    for (int i = 0; i < 4; ++i)
#pragma unroll
        for (int j = 0; j < 4; ++j)
            acc[i][j] = (f32x4){0.f, 0.f, 0.f, 0.f};

    int kmax = causal ? (m0 + 128 < K ? m0 + 128 : K) : K;

    // async-staging geometry: issue i covers tile rows [i*64+wave*16, +16)
    int srow = wave * 16 + (lane >> 2);      // + 64*i
    int scol = (lane & 3) * 8;               // k-elems within row

    for (int k0 = 0; k0 < kmax; k0 += 32) {
        async16(Ab + (size_t)(m0 + srow) * K + k0 + scol, (short*)At + wave * 512);
        async16(Ab + (size_t)(m0 + 64 + srow) * K + k0 + scol, (short*)At + 2048 + wave * 512);
        async16(Bb + (size_t)(n0 + srow) * K + k0 + scol, (short*)Bt + wave * 512);
        async16(Bb + (size_t)(n0 + 64 + srow) * K + k0 + scol, (short*)Bt + 2048 + wave * 512);
        __syncthreads();   // drains vmcnt (async) before reads

        bf16x8 af[4], bfr[4];
#pragma unroll
        for (int mi = 0; mi < 4; ++mi)
            af[mi] = *(const bf16x8*)&At[(wy * 64 + mi * 16 + l15) * 32 + quad * 8];
#pragma unroll
        for (int ni = 0; ni < 4; ++ni)
            bfr[ni] = *(const bf16x8*)&Bt[(wx * 64 + ni * 16 + l15) * 32 + quad * 8];
#pragma unroll
        for (int mi = 0; mi < 4; ++mi)
#pragma unroll
            for (int ni = 0; ni < 4; ++ni)
                acc[mi][ni] = __builtin_amdgcn_mfma_f32_16x16x32_bf16(
                    af[mi], bfr[ni], acc[mi][ni], 0, 0, 0);
        __syncthreads();   // protect tiles before next stage
    }

    // ---- epilogue ----
#pragma unroll
    for (int ni = 0; ni < 4; ++ni) {
        int col = n0 + wx * 64 + ni * 16 + l15;
        float bv = (EPI != 0) ? bias[col] : 0.f;
#pragma unroll
        for (int mi = 0; mi < 4; ++mi) {
            int row0 = m0 + wy * 64 + mi * 16 + quad * 4;
#pragma unroll
            for (int r = 0; r < 4; ++r) {
                size_t idx = (size_t)(row0 + r) * N + col;
                float val = acc[mi][ni][r];
                if constexpr (EPI == 0) {
                    ((bf16*)Cout)[(size_t)blockIdx.z * sC + idx] = __float2bfloat16(val);
                } else if constexpr (EPI == 1) {
                    ((float*)Cout)[idx] = val + bv + Res[idx];
                } else {
                    val += bv;
                    val = 0.5f * val * (1.f + erff(val * 0.70710678118654752f));
                    ((bf16*)Cout)[idx] = __float2bfloat16(val);
                }
            }
        }
    }
}

// ---------------------------------------------------------------------------
// Workspace (peak 62 MB):
//   [0,16)  : hnorm bf16 -> attn bf16 (step4 out) -> mnorm bf16 (step6 out)
//   [16,18) : qg fp32   [18,20): kg fp32
//   [20,36) : hnormT bf16                 -+ tbuf bf16 [20,52) after step 4
//   [36,52) : qkraw+uvT (pre-buildM) -> M -+
//   [52,54) : proj_w bf16   [54,58): up_w bf16   [58,62): down_w bf16
//   h1 lives in d_out (fp32); final GEMM does same-index RMW (alias-safe).
// ---------------------------------------------------------------------------
extern "C" void kernel_launch(void* const* d_in, const int* in_sizes, int n_in,
                              void* d_out, int out_size, void* d_ws, size_t ws_size,
                              hipStream_t stream) {
    const float* h           = (const float*)d_in[0];
    const float* k_base      = (const float*)d_in[1];
    const float* decay_logit = (const float*)d_in[2];
    const float* gate_logit  = (const float*)d_in[3];
    const float* alpha_logit = (const float*)d_in[4];
    const float* u           = (const float*)d_in[5];
    const float* v           = (const float*)d_in[6];
    const float* proj_w      = (const float*)d_in[7];
    const float* proj_b      = (const float*)d_in[8];
    const float* norm1_scale = (const float*)d_in[9];
    const float* norm2_scale = (const float*)d_in[10];
    const float* up_w        = (const float*)d_in[11];
    const float* up_b        = (const float*)d_in[12];
    const float* down_w      = (const float*)d_in[13];
    const float* down_b      = (const float*)d_in[14];

    const size_t MB = 1048576;
    char* ws = (char*)d_ws;
    bf16*  hnorm   = (bf16*)(ws);                  // 16 MB
    float* qg      = (float*)(ws + 16 * MB);       //  2 MB
    float* kg      = (float*)(ws + 18 * MB);       //  2 MB
    bf16*  hnormT  = (bf16*)(ws + 20 * MB);        // 16 MB
    bf16*  Mbuf    = (bf16*)(ws + 36 * MB);        // 16 MB
    bf16*  qkraw   = (bf16*)(ws + 36 * MB);        //  2 MB (dead before buildM)
    bf16*  uvT     = (bf16*)(ws + 39 * MB);        // 256 KB (dead before buildM)
    bf16*  proj_wb = (bf16*)(ws + 52 * MB);        //  2 MB
    bf16*  up_wb   = (bf16*)(ws + 54 * MB);        //  4 MB
    bf16*  down_wb = (bf16*)(ws + 58 * MB);        //  4 MB
    bf16*  attn    = hnorm;                        // [0,16) after qk GEMM
    bf16*  mnorm   = hnorm;
    bf16*  tbuf    = hnormT;                       // [20,52) after step 4
    float* h1      = (float*)d_out;

    // 0. weight conversions (independent of data path)
    convert_kernel<<<D_ * D_ / 2048, 256, 0, stream>>>(proj_w, proj_wb, D_ * D_);
    convert_kernel<<<2 * D_ * D_ / 2048, 256, 0, stream>>>(up_w, up_wb, 2 * D_ * D_);
    convert_kernel<<<2 * D_ * D_ / 2048, 256, 0, stream>>>(down_w, down_wb, 2 * D_ * D_);
    uvT_kernel<<<dim3(D_ / 64, 1, 2), 256, 0, stream>>>(u, v, uvT);

    // 1. h_norm = rmsnorm(h, norm1_scale)
    rmsnorm_kernel<<<B_ * W_, 256, 0, stream>>>(h, norm1_scale, hnorm);

    // 1b. hnormT[b][d][j] = hnorm[b][j][d]
    transpose_kernel<<<dim3(W_ / 64, D_ / 64, B_), 256, 0, stream>>>(hnorm, hnormT);

    // 2. qkraw = hnorm @ [u|v]   (M=8192, N=128, K=1024)
    mgemm_kernel<0><<<dim3(1, B_ * W_ / 128, 1), 256, 0, stream>>>(
        hnorm, uvT, nullptr, nullptr, qkraw, B_ * W_, 128, D_, 0, 0, 0, 0);

    // 2b. l2norm halves + gamma^{+/-i} scaling -> qg, kg (fp32)
    qk_epilogue_kernel<<<B_ * W_, 128, 0, stream>>>(qkraw, decay_logit, qg, kg);

    // 3. M = causal * (gate*k_base + alpha*scores)
    buildM_kernel<<<dim3(W_ / 32, W_ / 32, B_), dim3(16, 16), 0, stream>>>(
        qg, kg, k_base, gate_logit, alpha_logit, Mbuf);

    // 4. attn = M @ hnorm  (B-operand = hnormT, batched, causal k-truncation)
    mgemm_kernel<0><<<dim3(D_ / 128, W_ / 128, B_), 256, 0, stream>>>(
        Mbuf, hnormT, nullptr, nullptr, attn, W_, D_, W_,
        (long)W_ * W_, (long)W_ * D_, (long)W_ * D_, 1);

    // 5. h1 = h + attn @ proj_w^T + proj_b   -> d_out (fp32)
    mgemm_kernel<1><<<dim3(D_ / 128, B_ * W_ / 128, 1), 256, 0, stream>>>(
        attn, proj_wb, h, proj_b, h1, B_ * W_, D_, D_, 0, 0, 0, 0);

    // 6. mnorm = rmsnorm(h1, norm2_scale)
    rmsnorm_kernel<<<B_ * W_, 256, 0, stream>>>(h1, norm2_scale, mnorm);

    // 7. t = gelu(mnorm @ up_w^T + up_b)     -> tbuf (bf16)
    mgemm_kernel<2><<<dim3(2 * D_ / 128, B_ * W_ / 128, 1), 256, 0, stream>>>(
        mnorm, up_wb, nullptr, up_b, tbuf, B_ * W_, 2 * D_, D_, 0, 0, 0, 0);

    // 8. out = h1 + t @ down_w^T + down_b    (h1 aliases d_out: same-idx RMW)
    mgemm_kernel<1><<<dim3(D_ / 128, B_ * W_ / 128, 1), 256, 0, stream>>>(
        tbuf, down_wb, h1, down_b, (float*)d_out, B_ * W_, D_, 2 * D_, 0, 0, 0, 0);
}

// Round 6
// 383.757 us; speedup vs baseline: 4.2512x; 1.0741x over previous
//
#include <hip/hip_runtime.h>
#include <hip/hip_bf16.h>
#include <math.h>

#define B_ 8
#define W_ 1024
#define D_ 1024
#define R_ 64

typedef __hip_bfloat16 bf16;
typedef __attribute__((ext_vector_type(8))) short bf16x8;   // MFMA A/B frag (4 VGPRs)
typedef __attribute__((ext_vector_type(4))) float f32x4;    // MFMA C/D frag

__device__ __forceinline__ float tof(bf16 x) { return __bfloat162float(x); }
__device__ __forceinline__ short f2bs(float f) {
    bf16 b = __float2bfloat16(f);
    return *(short*)&b;
}

// async global->LDS, 16 bytes/lane; LDS dest = wave-uniform base + lane*16
__device__ __forceinline__ void async16(const void* g, void* l) {
    __builtin_amdgcn_global_load_lds(
        (const __attribute__((address_space(1))) unsigned int*)g,
        (__attribute__((address_space(3))) unsigned int*)l,
        16, 0, 0);
}

// ---------------------------------------------------------------------------
// RMSNorm: one block (256 threads) per row of D_=1024. fp32 in, bf16 out.
// ---------------------------------------------------------------------------
__global__ __launch_bounds__(256)
void rmsnorm_kernel(const float* __restrict__ src, const float* __restrict__ scale,
                    bf16* __restrict__ dst) {
    int row = blockIdx.x;
    const float* x = src + (size_t)row * D_;
    bf16* y = dst + (size_t)row * D_;
    float xv[4];
    float ss = 0.f;
#pragma unroll
    for (int it = 0; it < 4; ++it) {
        int d = threadIdx.x + it * 256;
        xv[it] = x[d];
        ss += xv[it] * xv[it];
    }
#pragma unroll
    for (int off = 32; off; off >>= 1) ss += __shfl_down(ss, off, 64);
    __shared__ float red[4];
    __shared__ float invs;
    int lane = threadIdx.x & 63, wid = threadIdx.x >> 6;
    if (lane == 0) red[wid] = ss;
    __syncthreads();
    if (threadIdx.x == 0) {
        float t = red[0] + red[1] + red[2] + red[3];
        invs = rsqrtf(t / (float)D_ + 1e-8f);
    }
    __syncthreads();
    float inv = invs;
#pragma unroll
    for (int it = 0; it < 4; ++it) {
        int d = threadIdx.x + it * 256;
        y[d] = __float2bfloat16(xv[it] * inv * scale[d]);
    }
}

// ---------------------------------------------------------------------------
// 64x64 LDS-tiled transpose: src[b][j][d] -> dst[b][d][j]  (bf16)
// ---------------------------------------------------------------------------
__global__ __launch_bounds__(256)
void transpose_kernel(const bf16* __restrict__ src, bf16* __restrict__ dst) {
    int b = blockIdx.z;
    int j0 = blockIdx.x * 64, d0 = blockIdx.y * 64;
    __shared__ short Ts[64][72];
    const bf16* S = src + (size_t)b * W_ * D_;
    bf16* Dd = dst + (size_t)b * W_ * D_;
    int tid = threadIdx.x;
    int r = tid >> 3, c = (tid & 7) * 8;
#pragma unroll
    for (int p = 0; p < 2; ++p) {
        int j = r + p * 32;
        bf16x8 vv = *(const bf16x8*)&S[(size_t)(j0 + j) * D_ + d0 + c];
#pragma unroll
        for (int e = 0; e < 8; ++e) Ts[j][c + e] = vv[e];
    }
    __syncthreads();
#pragma unroll
    for (int p = 0; p < 2; ++p) {
        int d = r + p * 32;
        bf16x8 vv;
#pragma unroll
        for (int e = 0; e < 8; ++e) vv[e] = Ts[c + e][d];
        *(bf16x8*)&Dd[(size_t)(d0 + d) * W_ + j0 + c] = vv;
    }
}

// ---------------------------------------------------------------------------
// uvT[r][d] (bf16, [128][1024]) from u[d][64] (z=0) and v[d][64] (z=1).
// ---------------------------------------------------------------------------
__global__ __launch_bounds__(256)
void uvT_kernel(const float* __restrict__ u, const float* __restrict__ v,
                bf16* __restrict__ uvT) {
    int g = blockIdx.z;
    int d0 = blockIdx.x * 64;
    const float* src = g ? v : u;
    __shared__ float Ts[64][65];
    int tid = threadIdx.x;
#pragma unroll
    for (int e = 0; e < 16; ++e) {
        int idx = tid + e * 256;
        int drow = idx >> 6, rcol = idx & 63;
        Ts[drow][rcol] = src[(size_t)(d0 + drow) * 64 + rcol];
    }
    __syncthreads();
#pragma unroll
    for (int e = 0; e < 16; ++e) {
        int idx = tid + e * 256;
        int orow = idx >> 6, ocol = idx & 63;
        uvT[(size_t)(g * 64 + orow) * D_ + d0 + ocol] = __float2bfloat16(Ts[ocol][orow]);
    }
}

// ---------------------------------------------------------------------------
// fp32 -> bf16 elementwise convert (n multiple of 2048).
// ---------------------------------------------------------------------------
__global__ __launch_bounds__(256)
void convert_kernel(const float* __restrict__ src, bf16* __restrict__ dst, int n) {
    int idx = (blockIdx.x * 256 + threadIdx.x) * 8;
    if (idx >= n) return;
    float4 f0 = *(const float4*)(src + idx);
    float4 f1 = *(const float4*)(src + idx + 4);
    bf16x8 p;
    p[0] = f2bs(f0.x); p[1] = f2bs(f0.y); p[2] = f2bs(f0.z); p[3] = f2bs(f0.w);
    p[4] = f2bs(f1.x); p[5] = f2bs(f1.y); p[6] = f2bs(f1.z); p[7] = f2bs(f1.w);
    *(bf16x8*)(dst + idx) = p;
}

// ---------------------------------------------------------------------------
// qk epilogue: l2norm halves of qkraw rows + gamma^{+/-i} -> qg, kg (fp32).
// ---------------------------------------------------------------------------
__global__ __launch_bounds__(128)
void qk_epilogue_kernel(const bf16* __restrict__ qkraw,
                        const float* __restrict__ decay_logit,
                        float* __restrict__ qg, float* __restrict__ kg) {
    int row = blockIdx.x;          // b*W + i
    int i = row & (W_ - 1);
    int t = threadIdx.x;
    int r = t & 63;
    bool isK = t >= 64;
    float val = tof(qkraw[(size_t)row * 128 + t]);
    float sq = val * val;
#pragma unroll
    for (int off = 32; off; off >>= 1) sq += __shfl_xor(sq, off, 64);
    val = val / fmaxf(sqrtf(sq), 1e-8f);

    float dl = decay_logit[r];
    float gamma = 0.15f + 0.85f * (1.f / (1.f + expf(-dl)));
    float lg = logf(gamma);
    float e = isK ? expf(-(float)i * lg) : expf((float)i * lg);
    float o = val * e;
    if (isK) kg[(size_t)row * R_ + r] = o;
    else     qg[(size_t)row * R_ + r] = o;
}

// ---------------------------------------------------------------------------
// M[b,i,j] = (j<=i) ? gate*k_base[i,j] + alpha * dot(qg[b,i,:], kg[b,j,:]) : 0
// ---------------------------------------------------------------------------
__global__ __launch_bounds__(256)
void buildM_kernel(const float* __restrict__ qg, const float* __restrict__ kg,
                   const float* __restrict__ k_base,
                   const float* __restrict__ gate_logit,
                   const float* __restrict__ alpha_logit,
                   bf16* __restrict__ M) {
    int b = blockIdx.z;
    int ti = blockIdx.y, tj = blockIdx.x;
    int i0 = ti * 32, j0 = tj * 32;
    int tx = threadIdx.x, ty = threadIdx.y;
    bf16* Mb = M + (size_t)b * W_ * W_;
    const bf16 zero = __float2bfloat16(0.f);

    if (tj > ti) {
#pragma unroll
        for (int a = 0; a < 2; ++a)
#pragma unroll
            for (int c = 0; c < 2; ++c)
                Mb[(size_t)(i0 + ty * 2 + a) * W_ + (j0 + tx * 2 + c)] = zero;
        return;
    }

    __shared__ float Qs[32][65];
    __shared__ float Ks[32][65];
    int tid = ty * 16 + tx;
    for (int e = tid; e < 32 * 64; e += 256) {
        int rr = e & 63, row = e >> 6;
        Qs[row][rr] = qg[((size_t)b * W_ + i0 + row) * R_ + rr];
        Ks[row][rr] = kg[((size_t)b * W_ + j0 + row) * R_ + rr];
    }
    __syncthreads();

    float acc[2][2] = {{0.f, 0.f}, {0.f, 0.f}};
#pragma unroll 8
    for (int r = 0; r < 64; ++r) {
        float qa = Qs[ty * 2 + 0][r], qb = Qs[ty * 2 + 1][r];
        float ka = Ks[tx * 2 + 0][r], kb = Ks[tx * 2 + 1][r];
        acc[0][0] += qa * ka; acc[0][1] += qa * kb;
        acc[1][0] += qb * ka; acc[1][1] += qb * kb;
    }

    float gate  = 1.f / (1.f + expf(-(*gate_logit)));
    float alpha = 1.f / (1.f + expf(-(*alpha_logit)));  // ALPHA_CAP = 1
#pragma unroll
    for (int a = 0; a < 2; ++a) {
#pragma unroll
        for (int c = 0; c < 2; ++c) {
            int i = i0 + ty * 2 + a, j = j0 + tx * 2 + c;
            float vkb = k_base[(size_t)i * W_ + j];
            float out = (j <= i) ? (gate * vkb + alpha * acc[a][c]) : 0.f;
            Mb[(size_t)i * W_ + j] = __float2bfloat16(out);
        }
    }
}

// ---------------------------------------------------------------------------
// MFMA GEMM: C[m,n] = sum_k A[m,k]*B[n,k]  (A, B bf16, k-major)
// BM=BN=128, BK=32; 256 threads = 4 waves (2x2); wave does 4x4 of 16x16x32.
// Round-5 upgrades (from rocprof: 4.2e6 LDS conflicts, VALU 37% > Mfma 15%,
// occ 22%):
//  - XOR swizzle at 16B granularity: lane l stages global chunk
//    (l&3)^((l>>3)&3); reader takes slot quad^((l15>>1)&3). 4-way -> 2-way
//    (free) bank pattern, async-LDS contiguity preserved.
//  - Per-lane base pointers hoisted; K-loop does 4 pointer adds, no 64-bit mul.
//  - Double-buffered LDS (2x16KB), stage k+1 before computing k, ONE barrier
//    per iteration: MFMA burst hides the global->LDS latency.
// EPI 0: Cout bf16 = acc                       (batched via sC)
// EPI 1: Cout fp32 = acc + bias[n] + Res[idx]  (Res may alias Cout, same-idx)
// EPI 2: Cout bf16 = gelu_exact(acc + bias[n])
// ---------------------------------------------------------------------------
template<int EPI>
__global__ __launch_bounds__(256)
void mgemm_kernel(const bf16* __restrict__ A, const bf16* __restrict__ Bm,
                  const float* __restrict__ Res, const float* __restrict__ bias,
                  void* __restrict__ Cout,
                  int M, int N, int K,
                  long sA, long sB, long sC, int causal) {
    __shared__ __align__(16) short At[2][128 * 32];
    __shared__ __align__(16) short Bt[2][128 * 32];
    const bf16* Ab = A + (size_t)blockIdx.z * sA;
    const bf16* Bb = Bm + (size_t)blockIdx.z * sB;
    int m0 = blockIdx.y * 128, n0 = blockIdx.x * 128;
    int tid = threadIdx.x;
    int lane = tid & 63, wave = tid >> 6;
    int wy = wave >> 1, wx = wave & 1;
    int quad = lane >> 4, l15 = lane & 15;

    f32x4 acc[4][4];
#pragma unroll
    for (int i = 0; i < 4; ++i)
#pragma unroll
        for (int j = 0; j < 4; ++j)
            acc[i][j] = (f32x4){0.f, 0.f, 0.f, 0.f};

    int kmax = causal ? (m0 + 128 < K ? m0 + 128 : K) : K;
    int nIter = kmax >> 5;

    // ---- staging geometry (hoisted) ----
    // issue covers 16 rows: row = base + (lane>>2); chunk slot = lane&3;
    // source chunk = (lane&3) ^ ((lane>>3)&3)  [ (row>>1)&3 within group ]
    int srcChunk = ((lane & 3) ^ ((lane >> 3) & 3)) * 8;
    size_t rowA = (size_t)(m0 + wave * 16 + (lane >> 2)) * K;
    size_t rowB = (size_t)(n0 + wave * 16 + (lane >> 2)) * K;
    const bf16* aP0 = Ab + rowA + srcChunk;
    const bf16* aP1 = aP0 + (size_t)64 * K;
    const bf16* bP0 = Bb + rowB + srcChunk;
    const bf16* bP1 = bP0 + (size_t)64 * K;
    short* dA0[2] = { &At[0][wave * 512],        &At[1][wave * 512] };
    short* dA1[2] = { &At[0][2048 + wave * 512], &At[1][2048 + wave * 512] };
    short* dB0[2] = { &Bt[0][wave * 512],        &Bt[1][wave * 512] };
    short* dB1[2] = { &Bt[0][2048 + wave * 512], &Bt[1][2048 + wave * 512] };

    // reader swizzle (lane-constant, hoisted)
    int rswz = (quad ^ ((l15 >> 1) & 3)) * 8;

    // ---- prologue: stage tile 0 into buf 0 ----
    async16(aP0, dA0[0]); async16(aP1, dA1[0]);
    async16(bP0, dB0[0]); async16(bP1, dB1[0]);
    aP0 += 32; aP1 += 32; bP0 += 32; bP1 += 32;
    __syncthreads();

    for (int it = 0; it < nIter; ++it) {
        int cur = it & 1;
        if (it + 1 < nIter) {
            int nxt = cur ^ 1;
            async16(aP0, dA0[nxt]); async16(aP1, dA1[nxt]);
            async16(bP0, dB0[nxt]); async16(bP1, dB1[nxt]);
            aP0 += 32; aP1 += 32; bP0 += 32; bP1 += 32;
        }
        bf16x8 af[4], bfr[4];
#pragma unroll
        for (int mi = 0; mi < 4; ++mi)
            af[mi] = *(const bf16x8*)&At[cur][(wy * 64 + mi * 16 + l15) * 32 + rswz];
#pragma unroll
        for (int ni = 0; ni < 4; ++ni)
            bfr[ni] = *(const bf16x8*)&Bt[cur][(wx * 64 + ni * 16 + l15) * 32 + rswz];
#pragma unroll
        for (int mi = 0; mi < 4; ++mi)
#pragma unroll
            for (int ni = 0; ni < 4; ++ni)
                acc[mi][ni] = __builtin_amdgcn_mfma_f32_16x16x32_bf16(
                    af[mi], bfr[ni], acc[mi][ni], 0, 0, 0);
        // one barrier/iter: (a) next-buf async complete, (b) cur reads done
        __syncthreads();
    }

    // ---- epilogue ----
#pragma unroll
    for (int ni = 0; ni < 4; ++ni) {
        int col = n0 + wx * 64 + ni * 16 + l15;
        float bv = (EPI != 0) ? bias[col] : 0.f;
#pragma unroll
        for (int mi = 0; mi < 4; ++mi) {
            int row0 = m0 + wy * 64 + mi * 16 + quad * 4;
#pragma unroll
            for (int r = 0; r < 4; ++r) {
                size_t idx = (size_t)(row0 + r) * N + col;
                float val = acc[mi][ni][r];
                if constexpr (EPI == 0) {
                    ((bf16*)Cout)[(size_t)blockIdx.z * sC + idx] = __float2bfloat16(val);
                } else if constexpr (EPI == 1) {
                    ((float*)Cout)[idx] = val + bv + Res[idx];
                } else {
                    val += bv;
                    val = 0.5f * val * (1.f + erff(val * 0.70710678118654752f));
                    ((bf16*)Cout)[idx] = __float2bfloat16(val);
                }
            }
        }
    }
}

// ---------------------------------------------------------------------------
// Workspace (peak 62 MB):
//   [0,16)  : hnorm bf16 -> attn bf16 (step4 out) -> mnorm bf16 (step6 out)
//   [16,18) : qg fp32   [18,20): kg fp32
//   [20,36) : hnormT bf16                 -+ tbuf bf16 [20,52) after step 4
//   [36,52) : qkraw+uvT (pre-buildM) -> M -+
//   [52,54) : proj_w bf16   [54,58): up_w bf16   [58,62): down_w bf16
//   h1 lives in d_out (fp32); final GEMM does same-index RMW (alias-safe).
// ---------------------------------------------------------------------------
extern "C" void kernel_launch(void* const* d_in, const int* in_sizes, int n_in,
                              void* d_out, int out_size, void* d_ws, size_t ws_size,
                              hipStream_t stream) {
    const float* h           = (const float*)d_in[0];
    const float* k_base      = (const float*)d_in[1];
    const float* decay_logit = (const float*)d_in[2];
    const float* gate_logit  = (const float*)d_in[3];
    const float* alpha_logit = (const float*)d_in[4];
    const float* u           = (const float*)d_in[5];
    const float* v           = (const float*)d_in[6];
    const float* proj_w      = (const float*)d_in[7];
    const float* proj_b      = (const float*)d_in[8];
    const float* norm1_scale = (const float*)d_in[9];
    const float* norm2_scale = (const float*)d_in[10];
    const float* up_w        = (const float*)d_in[11];
    const float* up_b        = (const float*)d_in[12];
    const float* down_w      = (const float*)d_in[13];
    const float* down_b      = (const float*)d_in[14];

    const size_t MB = 1048576;
    char* ws = (char*)d_ws;
    bf16*  hnorm   = (bf16*)(ws);                  // 16 MB
    float* qg      = (float*)(ws + 16 * MB);       //  2 MB
    float* kg      = (float*)(ws + 18 * MB);       //  2 MB
    bf16*  hnormT  = (bf16*)(ws + 20 * MB);        // 16 MB
    bf16*  Mbuf    = (bf16*)(ws + 36 * MB);        // 16 MB
    bf16*  qkraw   = (bf16*)(ws + 36 * MB);        //  2 MB (dead before buildM)
    bf16*  uvT     = (bf16*)(ws + 39 * MB);        // 256 KB (dead before buildM)
    bf16*  proj_wb = (bf16*)(ws + 52 * MB);        //  2 MB
    bf16*  up_wb   = (bf16*)(ws + 54 * MB);        //  4 MB
    bf16*  down_wb = (bf16*)(ws + 58 * MB);        //  4 MB
    bf16*  attn    = hnorm;                        // [0,16) after qk GEMM
    bf16*  mnorm   = hnorm;
    bf16*  tbuf    = hnormT;                       // [20,52) after step 4
    float* h1      = (float*)d_out;

    // 0. weight conversions (independent of data path)
    convert_kernel<<<D_ * D_ / 2048, 256, 0, stream>>>(proj_w, proj_wb, D_ * D_);
    convert_kernel<<<2 * D_ * D_ / 2048, 256, 0, stream>>>(up_w, up_wb, 2 * D_ * D_);
    convert_kernel<<<2 * D_ * D_ / 2048, 256, 0, stream>>>(down_w, down_wb, 2 * D_ * D_);
    uvT_kernel<<<dim3(D_ / 64, 1, 2), 256, 0, stream>>>(u, v, uvT);

    // 1. h_norm = rmsnorm(h, norm1_scale)
    rmsnorm_kernel<<<B_ * W_, 256, 0, stream>>>(h, norm1_scale, hnorm);

    // 1b. hnormT[b][d][j] = hnorm[b][j][d]
    transpose_kernel<<<dim3(W_ / 64, D_ / 64, B_), 256, 0, stream>>>(hnorm, hnormT);

    // 2. qkraw = hnorm @ [u|v]   (M=8192, N=128, K=1024)
    mgemm_kernel<0><<<dim3(1, B_ * W_ / 128, 1), 256, 0, stream>>>(
        hnorm, uvT, nullptr, nullptr, qkraw, B_ * W_, 128, D_, 0, 0, 0, 0);

    // 2b. l2norm halves + gamma^{+/-i} scaling -> qg, kg (fp32)
    qk_epilogue_kernel<<<B_ * W_, 128, 0, stream>>>(qkraw, decay_logit, qg, kg);

    // 3. M = causal * (gate*k_base + alpha*scores)
    buildM_kernel<<<dim3(W_ / 32, W_ / 32, B_), dim3(16, 16), 0, stream>>>(
        qg, kg, k_base, gate_logit, alpha_logit, Mbuf);

    // 4. attn = M @ hnorm  (B-operand = hnormT, batched, causal k-truncation)
    mgemm_kernel<0><<<dim3(D_ / 128, W_ / 128, B_), 256, 0, stream>>>(
        Mbuf, hnormT, nullptr, nullptr, attn, W_, D_, W_,
        (long)W_ * W_, (long)W_ * D_, (long)W_ * D_, 1);

    // 5. h1 = h + attn @ proj_w^T + proj_b   -> d_out (fp32)
    mgemm_kernel<1><<<dim3(D_ / 128, B_ * W_ / 128, 1), 256, 0, stream>>>(
        attn, proj_wb, h, proj_b, h1, B_ * W_, D_, D_, 0, 0, 0, 0);

    // 6. mnorm = rmsnorm(h1, norm2_scale)
    rmsnorm_kernel<<<B_ * W_, 256, 0, stream>>>(h1, norm2_scale, mnorm);

    // 7. t = gelu(mnorm @ up_w^T + up_b)     -> tbuf (bf16)
    mgemm_kernel<2><<<dim3(2 * D_ / 128, B_ * W_ / 128, 1), 256, 0, stream>>>(
        mnorm, up_wb, nullptr, up_b, tbuf, B_ * W_, 2 * D_, D_, 0, 0, 0, 0);

    // 8. out = h1 + t @ down_w^T + down_b    (h1 aliases d_out: same-idx RMW)
    mgemm_kernel<1><<<dim3(D_ / 128, B_ * W_ / 128, 1), 256, 0, stream>>>(
        tbuf, down_wb, h1, down_b, (float*)d_out, B_ * W_, D_, 2 * D_, 0, 0, 0, 0);
}